// Round 5
// baseline (749.641 us; speedup 1.0000x reference)
//
#include <hip/hip_runtime.h>
#include <math.h>
#include <stdint.h>

#define N_TOK 16384
#define DDIM  384
#define KCODE 8192
#define EMA   0.99f
#define EPS_F 1e-5f
#define MARGIN 0.4f
#define NB 16            // KCODE / 512 code-blocks in coarse pass

typedef _Float16 f16x8 __attribute__((ext_vector_type(8)));
typedef float    f32x4 __attribute__((ext_vector_type(4)));

#define AS1(p) ((const __attribute__((address_space(1))) uint32_t*)(p))
#define AS3(p) ((__attribute__((address_space(3))) uint32_t*)(p))

// ---- ws byte offsets (total 12,681,224 B — same footprint as proven R4) ----
// Region A [0, 12582912): phase1 partials etc; phase2 embed accumulator
#define OFF_PD1    0UL         // [NB][N_TOK] f32  (1 MB)
#define OFF_PI1    1048576UL   // [NB][N_TOK] i32
#define OFF_PD2    2097152UL   // [NB][N_TOK] f32
#define OFF_PRD    3145728UL   // [8][N_TOK] f32 rescore partial (0.5MB) + pad
#define OFF_PRI    4194304UL   // [8][N_TOK] i32
#define OFF_CB16   5242880UL   // [KCODE*DDIM] f16 (6,291,456 B)
#define OFF_CNORM  11534336UL  // [KCODE] f32 (32 KB)
#define OFF_FLIST  11567104UL  // [N_TOK] i32 (64 KB)
#define OFF_FCNT   11632640UL  // i32 + pad
#define OFF_EMBED  0UL         // phase2: [KCODE*DDIM] f32 (12.58 MB)
// outside region A:
#define OFF_WSIDX  12582912UL  // [N_TOK] i32
#define OFF_COUNTS 12648448UL  // [KCODE] f32
#define OFF_SUMSQ  12681216UL  // f32
#define OFF_NACC   12681220UL  // f32

// chunk swizzle: physical 8-f16 chunk for logical chunk c in row r
__device__ __forceinline__ int swz(int r, int c) { return c ^ ((r >> 1) & 3); }

// one wave per code: write f16 copy of codebook + row sumsq
__global__ void cvtcb_kernel(const float* __restrict__ cb, _Float16* __restrict__ cb16,
                             float* __restrict__ cnorm) {
    int code = (blockIdx.x * blockDim.x + threadIdx.x) >> 6;
    int lane = threadIdx.x & 63;
    if (code >= KCODE) return;
    const float* row = cb + (size_t)code * DDIM;
    _Float16* row16 = cb16 + (size_t)code * DDIM;
    float s = 0.f;
    #pragma unroll
    for (int r = 0; r < 6; r++) {
        float v = row[lane + 64 * r];
        s += v * v;
        row16[lane + 64 * r] = (_Float16)v;
    }
    #pragma unroll
    for (int off = 32; off > 0; off >>= 1) s += __shfl_down(s, off, 64);
    if (lane == 0) cnorm[code] = s;
}

// ---- coarse pass: f16 MFMA GEMM with per-token top-2 over 512-code blocks ----
// 512 threads = 8 waves (wy token-half x wx code-quarter); wave tile 64x128;
// block tile 128 tokens x 512 codes, BK=32, 12 K-iters.
__launch_bounds__(512)
__global__ void argmin16_kernel(const float* __restrict__ z, const _Float16* __restrict__ cb16,
                                const float* __restrict__ cnorm,
                                float* __restrict__ pd1, int* __restrict__ pi1,
                                float* __restrict__ pd2) {
    __shared__ _Float16 As[128 * 32];   //  8 KB (swizzled chunks)
    __shared__ _Float16 Bs[512 * 32];   // 32 KB (swizzled chunks)
    __shared__ float xd1[128 * 4];
    __shared__ float xd2[128 * 4];
    __shared__ int   xi1[128 * 4];

    const int tid  = threadIdx.x;
    const int lane = tid & 63;
    const int wv   = tid >> 6;
    const int wy   = wv >> 2;
    const int wx   = wv & 3;
    const int m0   = blockIdx.x * 128;
    const int n0   = blockIdx.y * 512;
    const int l15  = lane & 15;
    const int l4   = lane >> 4;

    f32x4 acc[4][8];
    #pragma unroll
    for (int i = 0; i < 4; i++)
        #pragma unroll
        for (int j = 0; j < 8; j++) acc[i][j] = (f32x4){0.f, 0.f, 0.f, 0.f};

    // A staging role: row = tid>>2 (0..127), logical chunk = tid&3
    const int arow = tid >> 2, ac = tid & 3;
    const int apos = arow * 32 + swz(arow, ac) * 8;
    const float* aglb = z + (size_t)(m0 + arow) * DDIM + ac * 8;
    // B staging role: 4 global_load_lds issues per wave; lane covers row lane>>2, phys chunk lane&3
    const int brow_i = lane >> 2;
    const int bclog  = (lane & 3) ^ ((lane >> 3) & 3);   // logical chunk whose data lands at phys lane&3
    // fragment read swizzle (row base multiples of 8 preserve (row>>1)&3 = (l15>>1)&3)
    const int fswz = (l4 ^ ((l15 >> 1) & 3)) * 8;

    for (int kc = 0; kc < DDIM; kc += 32) {
        { // stage A: fp32 -> f16 in flight, swizzled ds_write_b128
            float4 v0 = *(const float4*)(aglb + kc);
            float4 v1 = *(const float4*)(aglb + kc + 4);
            f16x8 h;
            h[0]=(_Float16)v0.x; h[1]=(_Float16)v0.y; h[2]=(_Float16)v0.z; h[3]=(_Float16)v0.w;
            h[4]=(_Float16)v1.x; h[5]=(_Float16)v1.y; h[6]=(_Float16)v1.z; h[7]=(_Float16)v1.w;
            *(f16x8*)(As + apos) = h;
        }
        // stage B: async direct-to-LDS, swizzle folded into per-lane global address
        #pragma unroll
        for (int r = 0; r < 4; r++) {
            int issue = wv * 4 + r;                       // 32 issues of 16 rows
            int row   = issue * 16 + brow_i;
            const _Float16* gp = cb16 + (size_t)(n0 + row) * DDIM + kc + bclog * 8;
            __builtin_amdgcn_global_load_lds(AS1(gp), AS3(Bs + issue * 512), 16, 0, 0);
        }
        __syncthreads();

        f16x8 af[4], bf[8];
        #pragma unroll
        for (int im = 0; im < 4; im++)
            af[im] = *(const f16x8*)(As + (wy * 64 + im * 16 + l15) * 32 + fswz);
        #pragma unroll
        for (int in = 0; in < 8; in++)
            bf[in] = *(const f16x8*)(Bs + (wx * 128 + in * 16 + l15) * 32 + fswz);
        #pragma unroll
        for (int im = 0; im < 4; im++)
            #pragma unroll
            for (int in = 0; in < 8; in++)
                acc[im][in] = __builtin_amdgcn_mfma_f32_16x16x32_f16(af[im], bf[in], acc[im][in], 0, 0, 0);
        __syncthreads();
    }

    // epilogue: dist = ||c||^2 - 2 z.c ; per-token top-2
    // C/D: col(code)=lane&15, row(token)=(lane>>4)*4+reg  [proven R4]
    float cn[8]; int cid[8];
    #pragma unroll
    for (int in = 0; in < 8; in++) {
        cid[in] = n0 + wx * 128 + in * 16 + l15;
        cn[in] = cnorm[cid[in]];
    }
    #pragma unroll
    for (int im = 0; im < 4; im++) {
        #pragma unroll
        for (int reg = 0; reg < 4; reg++) {
            float d1 = cn[0] - 2.f * acc[im][0][reg];
            int   i1 = cid[0];
            float d2 = 3.4e38f;
            #pragma unroll
            for (int in = 1; in < 8; in++) {
                float dd = cn[in] - 2.f * acc[im][in][reg];
                if (dd < d1) { d2 = d1; d1 = dd; i1 = cid[in]; }
                else d2 = fminf(d2, dd);
            }
            #pragma unroll
            for (int off = 1; off < 16; off <<= 1) {
                float od1 = __shfl_xor(d1, off, 16);
                int   oi1 = __shfl_xor(i1, off, 16);
                float od2 = __shfl_xor(d2, off, 16);
                if (od1 < d1 || (od1 == d1 && oi1 < i1)) { d2 = fminf(d1, od2); d1 = od1; i1 = oi1; }
                else d2 = fminf(d2, od1);
            }
            if (l15 == 0) {
                int tl = wy * 64 + im * 16 + l4 * 4 + reg;
                xd1[tl * 4 + wx] = d1; xi1[tl * 4 + wx] = i1; xd2[tl * 4 + wx] = d2;
            }
        }
    }
    __syncthreads();
    if (tid < 128) {
        float d1 = xd1[tid * 4], d2 = xd2[tid * 4];
        int   i1 = xi1[tid * 4];
        #pragma unroll
        for (int x = 1; x < 4; x++) {
            float od1 = xd1[tid * 4 + x], od2 = xd2[tid * 4 + x];
            int   oi1 = xi1[tid * 4 + x];
            if (od1 < d1 || (od1 == d1 && oi1 < i1)) { d2 = fminf(d1, od2); d1 = od1; i1 = oi1; }
            else d2 = fminf(d2, od1);
        }
        size_t o = (size_t)blockIdx.y * N_TOK + m0 + tid;
        pd1[o] = d1; pi1[o] = i1; pd2[o] = d2;
    }
}

// merge NB coarse partials per token; flag near-ties (gap < MARGIN)
__global__ void topmerge_kernel(const float* __restrict__ pd1, const int* __restrict__ pi1,
                                const float* __restrict__ pd2,
                                int* __restrict__ ws_idx, float* __restrict__ out_idx,
                                int* __restrict__ fcnt, int* __restrict__ flist) {
    int t = blockIdx.x * blockDim.x + threadIdx.x;
    if (t >= N_TOK) return;
    float d1 = pd1[t], d2 = pd2[t];
    int   i1 = pi1[t];
    for (int nb = 1; nb < NB; nb++) {
        size_t o = (size_t)nb * N_TOK + t;
        float od1 = pd1[o], od2 = pd2[o];
        int   oi1 = pi1[o];
        if (od1 < d1 || (od1 == d1 && oi1 < i1)) { d2 = fminf(d1, od2); d1 = od1; i1 = oi1; }
        else d2 = fminf(d2, od1);
    }
    ws_idx[t] = i1;
    out_idx[t] = (float)i1;
    if (d2 - d1 < MARGIN) {
        int s = atomicAdd(fcnt, 1);
        flist[s] = t;
    }
}

// exact fp32 rescore: 8 code-splits (1024 codes) x groups of 16 tokens.
// thread = 4 codes x 16 tokens.
__launch_bounds__(256)
__global__ void rescore_kernel(const float* __restrict__ z, const float* __restrict__ cb,
                               const float* __restrict__ cnorm,
                               const int* __restrict__ flist, const int* __restrict__ fcnt,
                               float* __restrict__ prd, int* __restrict__ pri) {
    __shared__ float zt[16 * 384];    // 24 KB
    __shared__ float rd[16 * 4];
    __shared__ int   ri[16 * 4];
    const int tid = threadIdx.x;
    const int lane = tid & 63, wv = tid >> 6;
    const int s = blockIdx.x;
    const int count = fcnt[0];
    for (int g = blockIdx.y; g * 16 < count; g += 128) {
        #pragma unroll
        for (int r = 0; r < 6; r++) {
            int q = tid + r * 256;
            int j = q / 96, d4 = q % 96;
            int slot = g * 16 + j; if (slot >= count) slot = count - 1;
            int tok = flist[slot];
            *(float4*)(zt + j * 384 + d4 * 4) = *(const float4*)(z + (size_t)tok * DDIM + d4 * 4);
        }
        __syncthreads();

        float a[4][16];
        #pragma unroll
        for (int c = 0; c < 4; c++)
            #pragma unroll
            for (int t = 0; t < 16; t++) a[c][t] = 0.f;
        int code[4];
        #pragma unroll
        for (int c = 0; c < 4; c++) code[c] = s * 1024 + c * 256 + tid;

        for (int d4 = 0; d4 < 96; d4++) {
            float4 cv[4];
            #pragma unroll
            for (int c = 0; c < 4; c++)
                cv[c] = *(const float4*)(cb + (size_t)code[c] * DDIM + d4 * 4);
            #pragma unroll
            for (int t = 0; t < 16; t++) {
                float4 zv = *(const float4*)(zt + t * 384 + d4 * 4);
                #pragma unroll
                for (int c = 0; c < 4; c++) {
                    a[c][t] = fmaf(zv.x, cv[c].x, a[c][t]);
                    a[c][t] = fmaf(zv.y, cv[c].y, a[c][t]);
                    a[c][t] = fmaf(zv.z, cv[c].z, a[c][t]);
                    a[c][t] = fmaf(zv.w, cv[c].w, a[c][t]);
                }
            }
        }
        float bd[16]; int bi[16];
        #pragma unroll
        for (int t = 0; t < 16; t++) { bd[t] = 3.4e38f; bi[t] = 0; }
        #pragma unroll
        for (int c = 0; c < 4; c++) {
            float cnv = cnorm[code[c]];
            #pragma unroll
            for (int t = 0; t < 16; t++) {
                float dd = cnv - 2.f * a[c][t];
                if (dd < bd[t] || (dd == bd[t] && code[c] < bi[t])) { bd[t] = dd; bi[t] = code[c]; }
            }
        }
        #pragma unroll
        for (int t = 0; t < 16; t++) {
            float d = bd[t]; int i = bi[t];
            #pragma unroll
            for (int off = 32; off > 0; off >>= 1) {
                float od = __shfl_xor(d, off, 64);
                int   oi = __shfl_xor(i, off, 64);
                if (od < d || (od == d && oi < i)) { d = od; i = oi; }
            }
            if (lane == 0) { rd[t * 4 + wv] = d; ri[t * 4 + wv] = i; }
        }
        __syncthreads();
        if (tid < 16) {
            float d = rd[tid * 4]; int i = ri[tid * 4];
            #pragma unroll
            for (int x = 1; x < 4; x++) {
                float od = rd[tid * 4 + x]; int oi = ri[tid * 4 + x];
                if (od < d || (od == d && oi < i)) { d = od; i = oi; }
            }
            int slot = g * 16 + tid; if (slot >= count) slot = count - 1;
            int tok = flist[slot];
            prd[(size_t)s * N_TOK + tok] = d;
            pri[(size_t)s * N_TOK + tok] = i;
        }
        __syncthreads();
    }
}

__global__ void rsmerge_kernel(const float* __restrict__ prd, const int* __restrict__ pri,
                               const int* __restrict__ flist, const int* __restrict__ fcnt,
                               int* __restrict__ ws_idx, float* __restrict__ out_idx) {
    int slot = blockIdx.x * blockDim.x + threadIdx.x;
    if (slot >= fcnt[0]) return;
    int tok = flist[slot];
    float d = prd[tok]; int i = pri[tok];
    for (int s = 1; s < 8; s++) {
        float od = prd[(size_t)s * N_TOK + tok];
        int   oi = pri[(size_t)s * N_TOK + tok];
        if (od < d || (od == d && oi < i)) { d = od; i = oi; }
    }
    ws_idx[tok] = i;
    out_idx[tok] = (float)i;
}

__global__ void gather_scatter_kernel(const float* __restrict__ z, const float* __restrict__ cb,
                                      const int* __restrict__ ws_idx,
                                      float* __restrict__ out_q, float* __restrict__ embed_ws,
                                      float* __restrict__ counts, float* __restrict__ sumsq) {
    int t = (blockIdx.x * blockDim.x + threadIdx.x) >> 6;
    int lane = threadIdx.x & 63;
    if (t >= N_TOK) return;
    int k = ws_idx[t];
    const float* zr = z + (size_t)t * DDIM;
    const float* cr = cb + (size_t)k * DDIM;
    float* qr = out_q + (size_t)t * DDIM;
    float* er = embed_ws + (size_t)k * DDIM;
    float s = 0.f;
    #pragma unroll
    for (int r = 0; r < 6; r++) {
        int d = lane + 64 * r;
        float zv = zr[d];
        float qv = cr[d];
        qr[d] = qv;
        float df = zv - qv;
        s += df * df;
        atomicAdd(er + d, zv);
    }
    #pragma unroll
    for (int off = 32; off > 0; off >>= 1) s += __shfl_down(s, off, 64);
    if (lane == 0) {
        atomicAdd(sumsq, s);
        atomicAdd(counts + k, 1.0f);
    }
}

__global__ void cluster_kernel(const float* __restrict__ ema_cs, const float* __restrict__ counts,
                               float* __restrict__ out_ncs, float* __restrict__ n_acc,
                               const float* __restrict__ sumsq, float* __restrict__ out_loss) {
    int i = blockIdx.x * blockDim.x + threadIdx.x;
    float v = 0.f;
    if (i < KCODE) {
        v = EMA * ema_cs[i] + (1.f - EMA) * counts[i];
        out_ncs[i] = v;
    }
    __shared__ float sm[4];
    int lane = threadIdx.x & 63, w = threadIdx.x >> 6;
    #pragma unroll
    for (int off = 32; off > 0; off >>= 1) v += __shfl_down(v, off, 64);
    if (lane == 0) sm[w] = v;
    __syncthreads();
    if (threadIdx.x == 0) {
        atomicAdd(n_acc, sm[0] + sm[1] + sm[2] + sm[3]);
        if (blockIdx.x == 0) {
            out_loss[0] = 1.25f * sumsq[0] / (float)(N_TOK * DDIM);
        }
    }
}

__global__ void codebook_kernel(const float* __restrict__ ema_es, const float* __restrict__ embed_ws,
                                const float* __restrict__ ncs, const float* __restrict__ n_acc,
                                float* __restrict__ out_es, float* __restrict__ out_cb) {
    int i = blockIdx.x * blockDim.x + threadIdx.x;
    if (i >= KCODE * DDIM) return;
    float es = EMA * ema_es[i] + (1.f - EMA) * embed_ws[i];
    out_es[i] = es;
    int k = i / DDIM;
    float n = n_acc[0];
    float smooth = (ncs[k] + EPS_F) / (n + (float)KCODE * EPS_F) * n;
    out_cb[i] = es / smooth;
}

extern "C" void kernel_launch(void* const* d_in, const int* in_sizes, int n_in,
                              void* d_out, int out_size, void* d_ws, size_t ws_size,
                              hipStream_t stream) {
    const float* z       = (const float*)d_in[0];
    const float* cb      = (const float*)d_in[1];
    const float* ema_cs  = (const float*)d_in[2];
    const float* ema_es  = (const float*)d_in[3];

    float* out      = (float*)d_out;
    float* out_q    = out;
    float* out_idx  = out + 6291456;
    float* out_loss = out + 6307840;
    float* out_ncs  = out + 6307841;
    float* out_es   = out + 6316033;
    float* out_cb   = out + 9461761;

    char* w = (char*)d_ws;
    float*     pd1    = (float*)    (w + OFF_PD1);
    int*       pi1    = (int*)      (w + OFF_PI1);
    float*     pd2    = (float*)    (w + OFF_PD2);
    float*     prd    = (float*)    (w + OFF_PRD);
    int*       pri    = (int*)      (w + OFF_PRI);
    _Float16*  cb16   = (_Float16*) (w + OFF_CB16);
    float*     cnorm  = (float*)    (w + OFF_CNORM);
    int*       flist  = (int*)      (w + OFF_FLIST);
    int*       fcnt   = (int*)      (w + OFF_FCNT);
    float*     embed  = (float*)    (w + OFF_EMBED);
    int*       ws_idx = (int*)      (w + OFF_WSIDX);
    float*     counts = (float*)    (w + OFF_COUNTS);
    float*     sumsq  = (float*)    (w + OFF_SUMSQ);
    float*     n_acc  = (float*)    (w + OFF_NACC);

    hipMemsetAsync(w + OFF_FCNT, 0, 256, stream);
    hipMemsetAsync(w + OFF_COUNTS, 0, 32768 + 256, stream);     // counts + sumsq + n_acc

    cvtcb_kernel<<<KCODE / 4, 256, 0, stream>>>(cb, cb16, cnorm);

    dim3 grid_am(N_TOK / 128, KCODE / 512, 1);
    argmin16_kernel<<<grid_am, 512, 0, stream>>>(z, cb16, cnorm, pd1, pi1, pd2);

    topmerge_kernel<<<N_TOK / 256, 256, 0, stream>>>(pd1, pi1, pd2, ws_idx, out_idx, fcnt, flist);

    dim3 grid_rs(8, 128, 1);
    rescore_kernel<<<grid_rs, 256, 0, stream>>>(z, cb, cnorm, flist, fcnt, prd, pri);
    rsmerge_kernel<<<N_TOK / 256, 256, 0, stream>>>(prd, pri, flist, fcnt, ws_idx, out_idx);

    // phase1 scratch dead; reuse region A as embed-sum accumulator
    hipMemsetAsync(w + OFF_EMBED, 0, (size_t)KCODE * DDIM * sizeof(float), stream);

    gather_scatter_kernel<<<N_TOK * 64 / 256, 256, 0, stream>>>(z, cb, ws_idx, out_q, embed, counts, sumsq);
    cluster_kernel<<<(KCODE + 255) / 256, 256, 0, stream>>>(ema_cs, counts, out_ncs, n_acc, sumsq, out_loss);
    codebook_kernel<<<(KCODE * DDIM) / 256, 256, 0, stream>>>(ema_es, embed, out_ncs, n_acc, out_es, out_cb);
}